// Round 12
// baseline (306.109 us; speedup 1.0000x reference)
//
#include <hip/hip_runtime.h>
#include <math.h>

// ---------------------------------------------------------------------------
// AFNO3D + LoRA, B=4 H=W=L=64 C=64, modes kh<32 kw<32 kl<8, NB=8 BS=8 R=8.
//
// 5-kernel pipeline (intermediates in d_ws, ALL bf16-packed):
//   K1a: DFT-L (real->8 modes)   x -> y1[bh][kl][w][cp]     (radix-2 folded)
//   K1b: DFT-W (64 -> 32 modes)  y1 -> y2[b][kl][kw][h][cp] (radix-2 folded)
//   K2 : DFT-H + MLP(LoRA) + iDFT-H in LDS                  (radix-2 folded)
//   K3a: iDFT-W (E/O fold)       z2 -> zw[bh][w][kl][cp]
//   K3b: iDFT-L (l/l+32 fold) + residual,  zw,x -> out
//
// R12 change: k1a/k3b widened to 16 B/lane (float4 x/out, uint4 zw/y1;
//   4 channels per thread, 16 lanes per row). R11 ran the 768 MB of fp32
//   x/out streams at 8 B/lane -> ~50% implied HBM efficiency.
// k1b/kc/k3a unchanged (validated R11).
// x/out fp32. Ortho scaling: 1/512 in K2 (pre-MLP) and 1/512 in K3b.
// ---------------------------------------------------------------------------

#define PI2_64 0.09817477042468103f   // 2*pi/64

__device__ __forceinline__ float gelu_exact(float t) {
    return 0.5f * t * (1.0f + erff(t * 0.7071067811865475f));
}

// ---- bf16 pack/unpack (RNE round; unpack = pure bit ops) ----
__device__ __forceinline__ unsigned int f2bf(float f) {
    unsigned int u = __float_as_uint(f);
    return (u + 0x7FFFu + ((u >> 16) & 1u)) >> 16;
}
__device__ __forceinline__ uint2 pack4(float4 f) {
    return make_uint2(f2bf(f.x) | (f2bf(f.y) << 16),
                      f2bf(f.z) | (f2bf(f.w) << 16));
}
__device__ __forceinline__ float4 unpack4(uint2 u) {
    return make_float4(__uint_as_float(u.x << 16),
                       __uint_as_float(u.x & 0xFFFF0000u),
                       __uint_as_float(u.y << 16),
                       __uint_as_float(u.y & 0xFFFF0000u));
}

// ===========================================================================
// K1a: DFT along L (real -> 8 complex modes), radix-2 folded, 16 B/lane.
// Block = (bh, wg): 256 threads = 16 w x 16 cq (cq = 4 channels). Grid 1024.
// y1 uint2 layout: [bh][kl][w][cp]  (cp = c/2; 4 bf16 = (re0,im0,re1,im1)).
// This thread writes cp = 2cq, 2cq+1 as one uint4.
__global__ void __launch_bounds__(256) k1a_dft_l(const float* __restrict__ x,
                                                 unsigned int* __restrict__ y1f) {
    __shared__ float2 twT[8][32];        // 2 KB: twT[kl][l] = e(+kl*l/64), l<32
    int tid = threadIdx.x;
    if (tid < 256) {
        int k = tid >> 5, l = tid & 31;
        float s, c;
        sincosf(PI2_64 * (float)((k * l) & 63), &s, &c);
        twT[k][l] = make_float2(c, s);
    }
    __syncthreads();

    int bid = blockIdx.x;                // bh*4 + wg
    int wg = bid & 3, bh = bid >> 2;
    int cq = tid & 15, wl = tid >> 4;    // wl in [0,16)
    int w = wg * 16 + wl;
    const float* xp = x + (size_t)(bh * 64 + w) * 4096 + 4 * cq;

    float4 A0[8], A1[8];                 // c-pairs 2cq, 2cq+1
#pragma unroll
    for (int kl = 0; kl < 8; ++kl) {
        A0[kl] = make_float4(0.f, 0.f, 0.f, 0.f);
        A1[kl] = make_float4(0.f, 0.f, 0.f, 0.f);
    }

    for (int l0 = 0; l0 < 32; l0 += 2) {
        float4 v0  = *(const float4*)(xp + (l0 + 0) * 64);
        float4 v0p = *(const float4*)(xp + (l0 + 32) * 64);
        float4 v1  = *(const float4*)(xp + (l0 + 1) * 64);
        float4 v1p = *(const float4*)(xp + (l0 + 33) * 64);
        float4 E0 = make_float4(v0.x + v0p.x, v0.y + v0p.y, v0.z + v0p.z, v0.w + v0p.w);
        float4 O0 = make_float4(v0.x - v0p.x, v0.y - v0p.y, v0.z - v0p.z, v0.w - v0p.w);
        float4 E1 = make_float4(v1.x + v1p.x, v1.y + v1p.y, v1.z + v1p.z, v1.w + v1p.w);
        float4 O1 = make_float4(v1.x - v1p.x, v1.y - v1p.y, v1.z - v1p.z, v1.w - v1p.w);
#pragma unroll
        for (int kl = 0; kl < 8; ++kl) {
            float2 t0 = twT[kl][l0];
            float2 t1 = twT[kl][l0 + 1];
            float4 s0 = (kl & 1) ? O0 : E0;    // static parity per kl
            float4 s1 = (kl & 1) ? O1 : E1;
            A0[kl].x += s0.x * t0.x;  A0[kl].y -= s0.x * t0.y;   // e^{-i th}
            A0[kl].z += s0.y * t0.x;  A0[kl].w -= s0.y * t0.y;
            A1[kl].x += s0.z * t0.x;  A1[kl].y -= s0.z * t0.y;
            A1[kl].z += s0.w * t0.x;  A1[kl].w -= s0.w * t0.y;
            A0[kl].x += s1.x * t1.x;  A0[kl].y -= s1.x * t1.y;
            A0[kl].z += s1.y * t1.x;  A0[kl].w -= s1.y * t1.y;
            A1[kl].x += s1.z * t1.x;  A1[kl].y -= s1.z * t1.y;
            A1[kl].z += s1.w * t1.x;  A1[kl].w -= s1.w * t1.y;
        }
    }
    uint4* y1 = (uint4*)y1f;             // uint4 idx = uint2 idx / 2
    size_t base = (size_t)bh * 8192 + (size_t)w * 16 + cq;
#pragma unroll
    for (int kl = 0; kl < 8; ++kl) {
        uint2 p0 = pack4(A0[kl]);
        uint2 p1 = pack4(A1[kl]);
        y1[base + kl * 1024] = make_uint4(p0.x, p0.y, p1.x, p1.y);
    }
}

// ===========================================================================
// K1b: DFT along W (64 -> 32 modes), radix-2 folded.
// Block = (bh, kl), 256 threads. Grid 2048. Stages bf16 slab -> fp32 LDS.
__global__ void __launch_bounds__(256) k1b_dft_w(const unsigned int* __restrict__ y1f,
                                                 unsigned int* __restrict__ y2f) {
    __shared__ float4 sD[64 * 32];       // 32 KB  [w][cp]
    __shared__ float2 twT[32][32];       // 8 KB  twT[kw][w] = e(+kw*w/64), w<32
    int tid = threadIdx.x;
#pragma unroll
    for (int e = 0; e < 4; ++e) {
        int idx = e * 256 + tid;         // 1024 entries
        int k = idx >> 5, l = idx & 31;
        float s, c;
        sincosf(PI2_64 * (float)((k * l) & 63), &s, &c);
        twT[k][l] = make_float2(c, s);
    }
    int pos = blockIdx.x;                // bh*8 + kl
    int kl = pos & 7, bh = pos >> 3;
    const uint2* src = (const uint2*)y1f + (size_t)pos * 2048;
#pragma unroll
    for (int r = 0; r < 8; ++r)
        sD[r * 256 + tid] = unpack4(src[r * 256 + tid]);
    __syncthreads();

    int cp = tid & 31, kwg = tid >> 5;   // 8 kw-groups of 4
    float4 acc[4];
#pragma unroll
    for (int i = 0; i < 4; ++i) acc[i] = make_float4(0.f, 0.f, 0.f, 0.f);

    for (int w = 0; w < 32; ++w) {
        float4 d  = sD[w * 32 + cp];
        float4 dp = sD[(w + 32) * 32 + cp];
        float4 E = make_float4(d.x + dp.x, d.y + dp.y, d.z + dp.z, d.w + dp.w);
        float4 O = make_float4(d.x - dp.x, d.y - dp.y, d.z - dp.z, d.w - dp.w);
#pragma unroll
        for (int i = 0; i < 4; ++i) {
            float2 t = twT[kwg * 4 + i][w];
            float4 s = (i & 1) ? O : E;        // kw parity = i parity
            acc[i].x += s.x * t.x + s.y * t.y;  // * e^{-i th}
            acc[i].y += s.y * t.x - s.x * t.y;
            acc[i].z += s.z * t.x + s.w * t.y;
            acc[i].w += s.w * t.x - s.z * t.y;
        }
    }
    int b = bh >> 6, h = bh & 63;
    uint2* y2 = (uint2*)y2f;
#pragma unroll
    for (int i = 0; i < 4; ++i) {
        int kw = kwg * 4 + i;
        y2[((size_t)((b * 8 + kl) * 32 + kw) * 64 + h) * 32 + cp] = pack4(acc[i]);
    }
}

// ===========================================================================
// K2: fused DFT-H (64->32, *1/512) + block-diag complex MLP + iDFT-H (32->64).
// One block per (b,kw,kl). Radix-2 folded both transforms. bf16 I/O.
__global__ void __launch_bounds__(256) kc_h_mlp(
        const unsigned int* __restrict__ y2f, unsigned int* __restrict__ z2f,
        const float* __restrict__ w1, const float* __restrict__ b1,
        const float* __restrict__ w2, const float* __restrict__ b2,
        const float* __restrict__ la1rA, const float* __restrict__ la1rB,
        const float* __restrict__ la1iA, const float* __restrict__ la1iB,
        const float* __restrict__ la2rA, const float* __restrict__ la2rB,
        const float* __restrict__ la2iA, const float* __restrict__ la2iB) {
    __shared__ float2 sD[64][64];      // staged input -> folded E/O; sM2 overlay
    __shared__ float2 sT[32][34];      // 8.7 KB: T(h*kh)= (cos,-sin), h<32 kh<32
    __shared__ float2 sM[32][66];
    __shared__ float  sW[4][512];
    __shared__ float  sb1[128], sb2[128];
    int tid = threadIdx.x;
    int pos = blockIdx.x;              // (b*32+kw)*8 + kl
    int kl = pos & 7, kw = (pos >> 3) & 31, b = pos >> 8;

#pragma unroll
    for (int r = 0; r < 4; ++r) {
        int idx = r * 256 + tid;       // 1024 = 32 h x 32 kh
        int h = idx >> 5, kh = idx & 31;
        float sn, cs;
        sincosf(PI2_64 * (float)((h * kh) & 63), &sn, &cs);
        sT[h][kh] = make_float2(cs, -sn);
    }
    const uint2* src = (const uint2*)y2f + (size_t)((b * 8 + kl) * 32 + kw) * 2048;
#pragma unroll
    for (int r = 0; r < 8; ++r) {
        int idx = r * 256 + tid;       // 0..2047: h = idx>>5, cpair = idx&31
        *(float4*)(&sD[idx >> 5][(idx & 31) * 2]) = unpack4(src[idx]);
    }
    {   // LoRA-corrected weights
        const float* As[4]   = {la1rA, la1iA, la2rA, la2iA};
        const float* Bs[4]   = {la1rB, la1iB, la2rB, la2iB};
        const float* base[4] = {w1, w1 + 512, w2, w2 + 512};
#pragma unroll
        for (int e = 0; e < 8; ++e) {
            int flat = tid + e * 256;
            int mat = flat >> 9;
            int rem = flat & 511;
            int n = rem >> 6, i = (rem >> 3) & 7, o = rem & 7;
            const float* A  = As[mat] + n * 64 + i * 8;
            const float* Bp = Bs[mat] + n * 64 + o;
            float s = 0.f;
#pragma unroll
            for (int r = 0; r < 8; ++r) s += A[r] * Bp[r * 8];
            sW[mat][(i * 8 + o) * 8 + n] = base[mat][n * 64 + i * 8 + o] + 0.125f * s;
        }
        if (tid < 128) sb1[tid] = b1[tid];
        else           sb2[tid - 128] = b2[tid - 128];
    }
    __syncthreads();

    // ---- fold rows in place: sD[h] = D[h]+D[h+32], sD[h+32] = D[h]-D[h+32] --
    {
        float4* sd4 = (float4*)&sD[0][0];   // 64 rows x 32 f4
#pragma unroll
        for (int r = 0; r < 4; ++r) {
            int idx = r * 256 + tid;        // 1024 = 32 h x 32 cq
            int h = idx >> 5, cq = idx & 31;
            float4 a = sd4[h * 32 + cq];
            float4 c = sd4[(h + 32) * 32 + cq];
            sd4[h * 32 + cq]        = make_float4(a.x + c.x, a.y + c.y, a.z + c.z, a.w + c.w);
            sd4[(h + 32) * 32 + cq] = make_float4(a.x - c.x, a.y - c.y, a.z - c.z, a.w - c.w);
        }
    }
    __syncthreads();

    // ---- M[kh][c] = (1/512) * sum_{h<32} T[h][kh] * (E|O)[h][c], 4kh x 2c --
    {
        int kh0 = (tid >> 5) * 4;          // multiple of 4: parity of kh0+i = i&1
        int c0  = (tid & 31) * 2;
        float mr[4][2], mi[4][2];
#pragma unroll
        for (int i = 0; i < 4; ++i)
#pragma unroll
            for (int j = 0; j < 2; ++j) { mr[i][j] = 0.f; mi[i][j] = 0.f; }
        for (int h = 0; h < 32; ++h) {
            float4 dE = *(const float4*)(&sD[h][c0]);        // E rows
            float4 dO = *(const float4*)(&sD[h + 32][c0]);   // O rows
            float Er[2] = {dE.x, dE.z}, Ei[2] = {dE.y, dE.w};
            float Or[2] = {dO.x, dO.z}, Oi[2] = {dO.y, dO.w};
            const float4* tT = (const float4*)(&sT[h][kh0]);
            float4 u0 = tT[0], u1 = tT[1];
            float Tr[4] = {u0.x, u0.z, u1.x, u1.z};
            float Ti[4] = {u0.y, u0.w, u1.y, u1.w};
#pragma unroll
            for (int i = 0; i < 4; ++i) {
                const float* Dr = (i & 1) ? Or : Er;
                const float* Di = (i & 1) ? Oi : Ei;
#pragma unroll
                for (int j = 0; j < 2; ++j) {
                    mr[i][j] += Tr[i] * Dr[j] - Ti[i] * Di[j];
                    mi[i][j] += Tr[i] * Di[j] + Ti[i] * Dr[j];
                }
            }
        }
        const float sc = 1.0f / 512.0f;
#pragma unroll
        for (int i = 0; i < 4; ++i)
#pragma unroll
            for (int j = 0; j < 2; ++j)
                sM[kh0 + i][c0 + j] = make_float2(mr[i][j] * sc, mi[i][j] * sc);
    }
    __syncthreads();

    // ---- MLP per (kh, n) ----
    float2* sM2 = (float2*)&sD[0][0];   // [32][66]
    {
        int kh = tid >> 3, n = tid & 7;
        float xr[8], xi[8];
#pragma unroll
        for (int i = 0; i < 8; ++i) {
            float2 v = sM[kh][n * 8 + i];
            xr[i] = v.x; xi[i] = v.y;
        }
        float o1r[8], o1i[8];
#pragma unroll
        for (int o = 0; o < 8; ++o) {
            float br = sb1[n * 8 + o], bi = sb1[64 + n * 8 + o];
            float sr = br - bi, si = br + bi;
#pragma unroll
            for (int i = 0; i < 8; ++i) {
                float wr = sW[0][(i * 8 + o) * 8 + n];
                float wi = sW[1][(i * 8 + o) * 8 + n];
                sr += xr[i] * wr - xi[i] * wi;
                si += xi[i] * wr + xr[i] * wi;
            }
            o1r[o] = gelu_exact(sr);
            o1i[o] = gelu_exact(si);
        }
#pragma unroll
        for (int o = 0; o < 8; ++o) {
            float br = sb2[n * 8 + o], bi = sb2[64 + n * 8 + o];
            float sr = br - bi, si = br + bi;
#pragma unroll
            for (int i = 0; i < 8; ++i) {
                float wr = sW[2][(i * 8 + o) * 8 + n];
                float wi = sW[3][(i * 8 + o) * 8 + n];
                sr += o1r[i] * wr - o1i[i] * wi;
                si += o1i[i] * wr + o1r[i] * wi;
            }
            sM2[kh * 66 + n * 8 + o] = make_float2(sr, si);
        }
    }
    __syncthreads();

    // ---- iDFT-H folded: out[h]=SE+SO, out[h+32]=SE-SO (2h x 4c tile) ----
    {
        int h0 = (tid >> 4) * 2;           // h0 in {0,2,...,30}
        int c0 = (tid & 15) * 4;
        float SEr[2][4], SEi[2][4], SOr[2][4], SOi[2][4];
#pragma unroll
        for (int r = 0; r < 2; ++r)
#pragma unroll
            for (int j = 0; j < 4; ++j) {
                SEr[r][j] = 0.f; SEi[r][j] = 0.f;
                SOr[r][j] = 0.f; SOi[r][j] = 0.f;
            }
        for (int khp = 0; khp < 16; ++khp) {
#pragma unroll
            for (int par = 0; par < 2; ++par) {
                int kh = 2 * khp + par;
                float2 T0 = sT[h0 + 0][kh];
                float2 T1 = sT[h0 + 1][kh];
                const float4* tM = (const float4*)(sM2 + kh * 66 + c0);
                float4 m0 = tM[0], m1 = tM[1];
                float Mr[4] = {m0.x, m0.z, m1.x, m1.z};
                float Mi[4] = {m0.y, m0.w, m1.y, m1.w};
                float (*Sr)[4] = par ? SOr : SEr;
                float (*Si)[4] = par ? SOi : SEi;
                float Tr[2] = {T0.x, T1.x};
                float Ti[2] = {T0.y, T1.y};
#pragma unroll
                for (int r = 0; r < 2; ++r)
#pragma unroll
                    for (int j = 0; j < 4; ++j) {
                        // conj(T): stored (cos,-sin) -> multiply by (Tr, -Ti)
                        Sr[r][j] += Tr[r] * Mr[j] + Ti[r] * Mi[j];
                        Si[r][j] += Tr[r] * Mi[j] - Ti[r] * Mr[j];
                    }
            }
        }
        uint2* dst = (uint2*)z2f + (size_t)((b * 8 + kl) * 32 + kw) * 2048;
#pragma unroll
        for (int r = 0; r < 2; ++r) {
            int iA = (h0 + r) * 32 + (c0 >> 1);
            dst[iA]     = pack4(make_float4(SEr[r][0] + SOr[r][0], SEi[r][0] + SOi[r][0],
                                            SEr[r][1] + SOr[r][1], SEi[r][1] + SOi[r][1]));
            dst[iA + 1] = pack4(make_float4(SEr[r][2] + SOr[r][2], SEi[r][2] + SOi[r][2],
                                            SEr[r][3] + SOr[r][3], SEi[r][3] + SOi[r][3]));
            int iB = (h0 + 32 + r) * 32 + (c0 >> 1);
            dst[iB]     = pack4(make_float4(SEr[r][0] - SOr[r][0], SEi[r][0] - SOi[r][0],
                                            SEr[r][1] - SOr[r][1], SEi[r][1] - SOi[r][1]));
            dst[iB + 1] = pack4(make_float4(SEr[r][2] - SOr[r][2], SEi[r][2] - SOi[r][2],
                                            SEr[r][3] - SOr[r][3], SEi[r][3] - SOi[r][3]));
        }
    }
}

// ===========================================================================
// K3a: iDFT along W (32 modes -> 64), even/odd-kw fold. bf16 I/O.
// Block = (b, h, klq in [0,4)): 256 threads = 32 cp x 8 wq. Grid 1024.
__global__ void __launch_bounds__(256) k3a_idft_w(const unsigned int* __restrict__ z2f,
                                                  unsigned int* __restrict__ zwf) {
    __shared__ float4 sZ[2 * 32 * 32];   // 32 KB  [kli][kw][cp]
    __shared__ float2 twT[32][32];       // 8 KB   twT[w][kw] = e(+kw*w/64), w<32
    int tid = threadIdx.x;
#pragma unroll
    for (int e = 0; e < 4; ++e) {
        int idx = e * 256 + tid;         // 1024 entries
        int w = idx >> 5, kw = idx & 31;
        float s, c;
        sincosf(PI2_64 * (float)((w * kw) & 63), &s, &c);
        twT[w][kw] = make_float2(c, s);
    }
    int bid = blockIdx.x;                // (b*64+h)*4 + klq
    int klq = bid & 3, h = (bid >> 2) & 63, b = bid >> 8;
    const uint2* z2 = (const uint2*)z2f;
#pragma unroll
    for (int r = 0; r < 8; ++r) {
        int idx = r * 256 + tid;         // 0..2047 = (kli*32+kw)*32 + cp
        int row = idx >> 5, cp2 = idx & 31;
        int kli = row >> 5, kw = row & 31;
        sZ[idx] = unpack4(
            z2[((size_t)((b * 8 + klq * 2 + kli) * 32 + kw) * 64 + h) * 32 + cp2]);
    }
    __syncthreads();

    int cp = tid & 31, wq = tid >> 5;    // wq in [0,8)

    float4 E[2][4], O[2][4];
#pragma unroll
    for (int kli = 0; kli < 2; ++kli)
#pragma unroll
        for (int j = 0; j < 4; ++j) {
            E[kli][j] = make_float4(0.f, 0.f, 0.f, 0.f);
            O[kli][j] = make_float4(0.f, 0.f, 0.f, 0.f);
        }

    for (int kw = 0; kw < 32; kw += 2) {
#pragma unroll
        for (int kli = 0; kli < 2; ++kli) {
            float4 d = sZ[(kli * 32 + kw) * 32 + cp];
#pragma unroll
            for (int j = 0; j < 4; ++j) {
                float2 t = twT[wq * 4 + j][kw];
                E[kli][j].x += d.x * t.x - d.y * t.y;
                E[kli][j].y += d.y * t.x + d.x * t.y;
                E[kli][j].z += d.z * t.x - d.w * t.y;
                E[kli][j].w += d.w * t.x + d.z * t.y;
            }
        }
#pragma unroll
        for (int kli = 0; kli < 2; ++kli) {
            float4 d = sZ[(kli * 32 + kw + 1) * 32 + cp];
#pragma unroll
            for (int j = 0; j < 4; ++j) {
                float2 t = twT[wq * 4 + j][kw + 1];
                O[kli][j].x += d.x * t.x - d.y * t.y;
                O[kli][j].y += d.y * t.x + d.x * t.y;
                O[kli][j].z += d.z * t.x - d.w * t.y;
                O[kli][j].w += d.w * t.x + d.z * t.y;
            }
        }
    }
    uint2* zw = (uint2*)zwf;
    size_t slab = ((size_t)(b * 64 + h)) * 16384;   // 64w * 8kl * 32cp uint2
#pragma unroll
    for (int kli = 0; kli < 2; ++kli) {
        int kl = klq * 2 + kli;
#pragma unroll
        for (int j = 0; j < 4; ++j) {
            int w = wq * 4 + j;
            float4 e = E[kli][j], o = O[kli][j];
            zw[slab + ((size_t)w * 8 + kl) * 32 + cp] =
                pack4(make_float4(e.x + o.x, e.y + o.y, e.z + o.z, e.w + o.w));
            zw[slab + ((size_t)(w + 32) * 8 + kl) * 32 + cp] =
                pack4(make_float4(e.x - o.x, e.y - o.y, e.z - o.z, e.w - o.w));
        }
    }
}

// ===========================================================================
// K3b: iDFT along L (numpy irfft: Im(kl=0) dropped, modes 1..7 doubled),
// l/l+32 folded, + residual, 16 B/lane. Block = (bh, wg): 256 threads =
// 16 w x 16 cq (cq = 4 channels). Grid 1024. zw uint4; x/out float4.
__global__ void __launch_bounds__(256) k3b_idft_l(const float* __restrict__ x,
                                                  const unsigned int* __restrict__ zwf,
                                                  float* __restrict__ outp) {
    __shared__ float2 twA[8][32];        // 1 KB: twA[k][l] = e(+k*l/64), l<32
    int tid = threadIdx.x;
    if (tid < 256) {
        int k = tid >> 5, l = tid & 31;
        float s, c;
        sincosf(PI2_64 * (float)((k * l) & 63), &s, &c);
        twA[k][l] = make_float2(c, s);
    }
    __syncthreads();

    int bid = blockIdx.x;                // bh*4 + wg
    int wg = bid & 3, bh = bid >> 2;
    int cq = tid & 15, wl = tid >> 4;
    int w = wg * 16 + wl;

    // zw uint2 idx = (bh*64+w)*256 + kl*32 + cp ; uint4 idx = half of that
    const uint4* zw4 = (const uint4*)zwf;
    size_t zbase = ((size_t)(bh * 64 + w)) * 128 + cq;
    float4 z0[8], z1[8];                 // channels 4cq..4cq+1, 4cq+2..4cq+3
#pragma unroll
    for (int kl = 0; kl < 8; ++kl) {
        uint4 u = zw4[zbase + kl * 16];
        z0[kl] = unpack4(make_uint2(u.x, u.y));
        z1[kl] = unpack4(make_uint2(u.z, u.w));
    }

    float r00 = z0[0].x, r01 = z0[0].z;  // kl=0 real parts (Im dropped)
    float r10 = z1[0].x, r11 = z1[0].z;
#pragma unroll
    for (int kl = 1; kl < 8; ++kl) {     // pre-double modes 1..7
        z0[kl].x *= 2.f; z0[kl].y *= 2.f; z0[kl].z *= 2.f; z0[kl].w *= 2.f;
        z1[kl].x *= 2.f; z1[kl].y *= 2.f; z1[kl].z *= 2.f; z1[kl].w *= 2.f;
    }
    const size_t row = ((size_t)(bh * 64 + w)) * 4096;
    const float* xp = x + row + 4 * cq;
    float* op = outp + row + 4 * cq;
    const float sc = 1.0f / 512.0f;

    for (int l = 0; l < 32; ++l) {
        float4 a0 = *(const float4*)(xp + l * 64);
        float4 a1 = *(const float4*)(xp + (l + 32) * 64);
        float e00 = 0.f, e01 = 0.f, e10 = 0.f, e11 = 0.f;
        float o00 = 0.f, o01 = 0.f, o10 = 0.f, o11 = 0.f;
#pragma unroll
        for (int kl = 2; kl < 8; kl += 2) {
            float2 t = twA[kl][l];
            e00 += z0[kl].x * t.x - z0[kl].y * t.y;
            e01 += z0[kl].z * t.x - z0[kl].w * t.y;
            e10 += z1[kl].x * t.x - z1[kl].y * t.y;
            e11 += z1[kl].z * t.x - z1[kl].w * t.y;
        }
#pragma unroll
        for (int kl = 1; kl < 8; kl += 2) {
            float2 t = twA[kl][l];
            o00 += z0[kl].x * t.x - z0[kl].y * t.y;
            o01 += z0[kl].z * t.x - z0[kl].w * t.y;
            o10 += z1[kl].x * t.x - z1[kl].y * t.y;
            o11 += z1[kl].z * t.x - z1[kl].w * t.y;
        }
        float b00 = r00 + e00, b01 = r01 + e01;
        float b10 = r10 + e10, b11 = r11 + e11;
        *(float4*)(op + l * 64) = make_float4(
            (b00 + o00) * sc + a0.x, (b01 + o01) * sc + a0.y,
            (b10 + o10) * sc + a0.z, (b11 + o11) * sc + a0.w);
        *(float4*)(op + (l + 32) * 64) = make_float4(
            (b00 - o00) * sc + a1.x, (b01 - o01) * sc + a1.y,
            (b10 - o10) * sc + a1.z, (b11 - o11) * sc + a1.w);
    }
}

// ===========================================================================
extern "C" void kernel_launch(void* const* d_in, const int* in_sizes, int n_in,
                              void* d_out, int out_size, void* d_ws, size_t ws_size,
                              hipStream_t stream) {
    const float* x     = (const float*)d_in[0];
    const float* w1    = (const float*)d_in[1];
    const float* b1    = (const float*)d_in[2];
    const float* w2    = (const float*)d_in[3];
    const float* b2    = (const float*)d_in[4];
    const float* la1rA = (const float*)d_in[5];
    const float* la1rB = (const float*)d_in[6];
    const float* la1iA = (const float*)d_in[7];
    const float* la1iB = (const float*)d_in[8];
    const float* la2rA = (const float*)d_in[9];
    const float* la2rB = (const float*)d_in[10];
    const float* la2iA = (const float*)d_in[11];
    const float* la2iB = (const float*)d_in[12];
    float* out = (float*)d_out;

    unsigned int* ws = (unsigned int*)d_ws;
    unsigned int* y1 = ws;                 // 8388608 uint (33.5 MB)
    unsigned int* y2 = ws + 8388608;       // 4194304 uint (16.8 MB)
    unsigned int* z2 = ws + 12582912;      // 4194304 uint (16.8 MB)
    unsigned int* zw = ws + 16777216;      // 8388608 uint (33.5 MB)

    hipLaunchKernelGGL(k1a_dft_l,  dim3(1024), dim3(256), 0, stream, x, y1);
    hipLaunchKernelGGL(k1b_dft_w,  dim3(2048), dim3(256), 0, stream, y1, y2);
    hipLaunchKernelGGL(kc_h_mlp,   dim3(1024), dim3(256), 0, stream, y2, z2,
                       w1, b1, w2, b2, la1rA, la1rB, la1iA, la1iB,
                       la2rA, la2rB, la2iA, la2iB);
    hipLaunchKernelGGL(k3a_idft_w, dim3(1024), dim3(256), 0, stream, z2, zw);
    hipLaunchKernelGGL(k3b_idft_l, dim3(1024), dim3(256), 0, stream, x, zw, out);
}

// Round 13
// 281.686 us; speedup vs baseline: 1.0867x; 1.0867x over previous
//
#include <hip/hip_runtime.h>
#include <math.h>

// ---------------------------------------------------------------------------
// AFNO3D + LoRA, B=4 H=W=L=64 C=64, modes kh<32 kw<32 kl<8, NB=8 BS=8 R=8.
//
// 4-kernel pipeline (intermediates in d_ws, ALL bf16-packed):
//   K1 : fused DFT-L + DFT-W per (bh, c-half); slab in LDS (bf16, 69.7 KB)
//        x -> y2[b][kl][kw][h][cp]
//   K2 : DFT-H + MLP(LoRA) + iDFT-H in LDS (radix-2 folded, slim 43 KB LDS)
//   K3a: iDFT-W (E/O fold)       z2 -> zw[bh][w][kl][cp]
//   K3b: iDFT-L (l/l+32 fold) + residual,  zw,x -> out
//
// R13 change: (1) k1a+k1b fused via bf16 LDS slab (kills 67 MB y1 round-trip
//   + one launch; 256 thr, 2 blocks/CU — obeys the 256-thread/VGPR lessons
//   of R4-R9). (2) kc LDS 67->43 KB (bf16 staging + fold-on-the-fly + bf16
//   sM/sM2 with overlay) -> 3 blocks/CU.
// x/out fp32. Ortho scaling: 1/512 in K2 (pre-MLP) and 1/512 in K3b.
// ---------------------------------------------------------------------------

#define PI2_64 0.09817477042468103f   // 2*pi/64

__device__ __forceinline__ float gelu_exact(float t) {
    return 0.5f * t * (1.0f + erff(t * 0.7071067811865475f));
}

// ---- bf16 pack/unpack (RNE round; unpack = pure bit ops) ----
__device__ __forceinline__ unsigned int f2bf(float f) {
    unsigned int u = __float_as_uint(f);
    return (u + 0x7FFFu + ((u >> 16) & 1u)) >> 16;
}
__device__ __forceinline__ uint2 pack4(float4 f) {
    return make_uint2(f2bf(f.x) | (f2bf(f.y) << 16),
                      f2bf(f.z) | (f2bf(f.w) << 16));
}
__device__ __forceinline__ float4 unpack4(uint2 u) {
    return make_float4(__uint_as_float(u.x << 16),
                       __uint_as_float(u.x & 0xFFFF0000u),
                       __uint_as_float(u.y << 16),
                       __uint_as_float(u.y & 0xFFFF0000u));
}
__device__ __forceinline__ unsigned int pack2(float r, float i) {
    return f2bf(r) | (f2bf(i) << 16);
}
__device__ __forceinline__ float2 unpack2(unsigned int u) {
    return make_float2(__uint_as_float(u << 16),
                       __uint_as_float(u & 0xFFFF0000u));
}

// ===========================================================================
// K1: fused DFT-L + DFT-W.  Block = (bh, ch): 256 threads. Grid 512.
// Phase 1 (DFT-L, radix-2 folded): thread (wl=tid>>4, cp=tid&15) loops 4 w,
//   accumulates A[8] (f4 = 2 complex) and writes bf16 slab sY[kl][w][cp].
// Phase 2 (DFT-W, E/O fold): thread (kwh=tid>>7, kl=(tid>>4)&7, cp=tid&15)
//   single-pass over w with acc[16], writes y2.
// Slab stride 17 uint2/w-row (bank spread), 1089/kl.
__global__ void __launch_bounds__(256) k1_fused(const float* __restrict__ x,
                                                unsigned int* __restrict__ y2f) {
    __shared__ uint2  sY[8 * 1089];      // 69.7 KB bf16 slab
    __shared__ float2 twT1[8][32];       // e(+kl*l/64), l<32
    __shared__ float2 twT2[32][32];      // e(+kw*w/64), w<32
    int tid = threadIdx.x;
    {
        int k = tid >> 5, l = tid & 31;
        float s, c;
        sincosf(PI2_64 * (float)((k * l) & 63), &s, &c);
        twT1[k][l] = make_float2(c, s);
    }
#pragma unroll
    for (int e = 0; e < 4; ++e) {
        int idx = e * 256 + tid;
        int k = idx >> 5, l = idx & 31;
        float s, c;
        sincosf(PI2_64 * (float)((k * l) & 63), &s, &c);
        twT2[k][l] = make_float2(c, s);
    }
    __syncthreads();

    int bid = blockIdx.x;                // bh*2 + ch
    int ch = bid & 1, bh = bid >> 1;

    {   // ---- phase 1: DFT along L (radix-2 folded) ----
        int cp = tid & 15, wl = tid >> 4;
#pragma unroll
        for (int wi = 0; wi < 4; ++wi) {
            int w = wi * 16 + wl;
            const float* xp = x + (size_t)(bh * 64 + w) * 4096 + ch * 32 + 2 * cp;
            float4 A[8];
#pragma unroll
            for (int kl = 0; kl < 8; ++kl) A[kl] = make_float4(0.f, 0.f, 0.f, 0.f);
            for (int l0 = 0; l0 < 32; l0 += 2) {
                float2 v0  = *(const float2*)(xp + (l0 + 0) * 64);
                float2 v0p = *(const float2*)(xp + (l0 + 32) * 64);
                float2 v1  = *(const float2*)(xp + (l0 + 1) * 64);
                float2 v1p = *(const float2*)(xp + (l0 + 33) * 64);
                float2 E0 = make_float2(v0.x + v0p.x, v0.y + v0p.y);
                float2 O0 = make_float2(v0.x - v0p.x, v0.y - v0p.y);
                float2 E1 = make_float2(v1.x + v1p.x, v1.y + v1p.y);
                float2 O1 = make_float2(v1.x - v1p.x, v1.y - v1p.y);
#pragma unroll
                for (int kl = 0; kl < 8; ++kl) {
                    float2 t0 = twT1[kl][l0];
                    float2 t1 = twT1[kl][l0 + 1];
                    float2 s0 = (kl & 1) ? O0 : E0;
                    float2 s1 = (kl & 1) ? O1 : E1;
                    A[kl].x += s0.x * t0.x;  A[kl].y -= s0.x * t0.y;  // e^{-i th}
                    A[kl].z += s0.y * t0.x;  A[kl].w -= s0.y * t0.y;
                    A[kl].x += s1.x * t1.x;  A[kl].y -= s1.x * t1.y;
                    A[kl].z += s1.y * t1.x;  A[kl].w -= s1.y * t1.y;
                }
            }
#pragma unroll
            for (int kl = 0; kl < 8; ++kl)
                sY[kl * 1089 + w * 17 + cp] = pack4(A[kl]);
        }
    }
    __syncthreads();

    {   // ---- phase 2: DFT along W (64 -> 32 modes), E/O fold, 1 pass ----
        int cp = tid & 15, kl = (tid >> 4) & 7, kwh = tid >> 7;
        const uint2* row = &sY[kl * 1089];
        float4 acc[16];
#pragma unroll
        for (int i = 0; i < 16; ++i) acc[i] = make_float4(0.f, 0.f, 0.f, 0.f);

        for (int w = 0; w < 32; ++w) {
            float4 a = unpack4(row[w * 17 + cp]);
            float4 b4 = unpack4(row[(w + 32) * 17 + cp]);
            float4 E = make_float4(a.x + b4.x, a.y + b4.y, a.z + b4.z, a.w + b4.w);
            float4 O = make_float4(a.x - b4.x, a.y - b4.y, a.z - b4.z, a.w - b4.w);
#pragma unroll
            for (int i = 0; i < 16; ++i) {
                float2 t = twT2[kwh * 16 + i][w];
                float4 s = (i & 1) ? O : E;        // kw parity = i parity
                acc[i].x += s.x * t.x + s.y * t.y;  // * e^{-i th}
                acc[i].y += s.y * t.x - s.x * t.y;
                acc[i].z += s.z * t.x + s.w * t.y;
                acc[i].w += s.w * t.x - s.z * t.y;
            }
        }
        int b = bh >> 6, h = bh & 63;
        uint2* y2 = (uint2*)y2f;
#pragma unroll
        for (int i = 0; i < 16; ++i) {
            int kw = kwh * 16 + i;
            y2[((size_t)((b * 8 + kl) * 32 + kw) * 64 + h) * 32 + ch * 16 + cp] =
                pack4(acc[i]);
        }
    }
}

// ===========================================================================
// K2: fused DFT-H (64->32, *1/512) + block-diag complex MLP + iDFT-H (32->64).
// One block per (b,kw,kl). Radix-2 folded both transforms. bf16 I/O.
// R13: sDu staged bf16 (16 KB) + fold-on-the-fly; sM/sM2 bf16-pair packed;
// sM2 overlays dead sDu. Total LDS ~43 KB -> 3 blocks/CU.
__global__ void __launch_bounds__(256) kc_h_mlp(
        const unsigned int* __restrict__ y2f, unsigned int* __restrict__ z2f,
        const float* __restrict__ w1, const float* __restrict__ b1,
        const float* __restrict__ w2, const float* __restrict__ b2,
        const float* __restrict__ la1rA, const float* __restrict__ la1rB,
        const float* __restrict__ la1iA, const float* __restrict__ la1iB,
        const float* __restrict__ la2rA, const float* __restrict__ la2rB,
        const float* __restrict__ la2iA, const float* __restrict__ la2iB) {
    __shared__ uint2  sDu[64 * 32];    // 16 KB bf16 [h][cq]; later overlaid sM2
    __shared__ float2 sT[32][34];      // 8.7 KB: (cos,-sin)(h*kh), h<32 kh<32
    __shared__ unsigned int sMu[32 * 66];   // 8.4 KB bf16-pair M
    __shared__ float  sW[4][512];
    __shared__ float  sb1[128], sb2[128];
    unsigned int* sM2u = (unsigned int*)sDu;   // [32][66] bf16-pair, post-MLP
    int tid = threadIdx.x;
    int pos = blockIdx.x;              // (b*32+kw)*8 + kl
    int kl = pos & 7, kw = (pos >> 3) & 31, b = pos >> 8;

#pragma unroll
    for (int r = 0; r < 4; ++r) {
        int idx = r * 256 + tid;       // 1024 = 32 h x 32 kh
        int h = idx >> 5, kh = idx & 31;
        float sn, cs;
        sincosf(PI2_64 * (float)((h * kh) & 63), &sn, &cs);
        sT[h][kh] = make_float2(cs, -sn);
    }
    const uint2* src = (const uint2*)y2f + (size_t)((b * 8 + kl) * 32 + kw) * 2048;
#pragma unroll
    for (int r = 0; r < 8; ++r) {
        int idx = r * 256 + tid;       // [h][cq] : pure bf16 copy
        sDu[idx] = src[idx];
    }
    {   // LoRA-corrected weights
        const float* As[4]   = {la1rA, la1iA, la2rA, la2iA};
        const float* Bs[4]   = {la1rB, la1iB, la2rB, la2iB};
        const float* base[4] = {w1, w1 + 512, w2, w2 + 512};
#pragma unroll
        for (int e = 0; e < 8; ++e) {
            int flat = tid + e * 256;
            int mat = flat >> 9;
            int rem = flat & 511;
            int n = rem >> 6, i = (rem >> 3) & 7, o = rem & 7;
            const float* A  = As[mat] + n * 64 + i * 8;
            const float* Bp = Bs[mat] + n * 64 + o;
            float s = 0.f;
#pragma unroll
            for (int r = 0; r < 8; ++r) s += A[r] * Bp[r * 8];
            sW[mat][(i * 8 + o) * 8 + n] = base[mat][n * 64 + i * 8 + o] + 0.125f * s;
        }
        if (tid < 128) sb1[tid] = b1[tid];
        else           sb2[tid - 128] = b2[tid - 128];
    }
    __syncthreads();

    // ---- M[kh][c] = (1/512) * sum_{h<32} T[h][kh] * (E|O)[h][c], 4kh x 2c,
    //      fold E=D[h]+D[h+32], O=D[h]-D[h+32] on the fly ----
    {
        int kh0 = (tid >> 5) * 4;          // parity of kh0+i = i&1
        int cq  = tid & 31;                // uint2 col = 2 complex
        int c0f = cq * 2;                  // complex col
        float mr[4][2], mi[4][2];
#pragma unroll
        for (int i = 0; i < 4; ++i)
#pragma unroll
            for (int j = 0; j < 2; ++j) { mr[i][j] = 0.f; mi[i][j] = 0.f; }
        for (int h = 0; h < 32; ++h) {
            float4 a  = unpack4(sDu[h * 32 + cq]);         // row h
            float4 c4 = unpack4(sDu[(h + 32) * 32 + cq]);  // row h+32
            float Er[2] = {a.x + c4.x, a.z + c4.z};
            float Ei[2] = {a.y + c4.y, a.w + c4.w};
            float Or[2] = {a.x - c4.x, a.z - c4.z};
            float Oi[2] = {a.y - c4.y, a.w - c4.w};
            const float4* tT = (const float4*)(&sT[h][kh0]);
            float4 u0 = tT[0], u1 = tT[1];
            float Tr[4] = {u0.x, u0.z, u1.x, u1.z};
            float Ti[4] = {u0.y, u0.w, u1.y, u1.w};
#pragma unroll
            for (int i = 0; i < 4; ++i) {
                const float* Dr = (i & 1) ? Or : Er;
                const float* Di = (i & 1) ? Oi : Ei;
#pragma unroll
                for (int j = 0; j < 2; ++j) {
                    mr[i][j] += Tr[i] * Dr[j] - Ti[i] * Di[j];
                    mi[i][j] += Tr[i] * Di[j] + Ti[i] * Dr[j];
                }
            }
        }
        const float sc = 1.0f / 512.0f;
#pragma unroll
        for (int i = 0; i < 4; ++i)
#pragma unroll
            for (int j = 0; j < 2; ++j)
                sMu[(kh0 + i) * 66 + c0f + j] = pack2(mr[i][j] * sc, mi[i][j] * sc);
    }
    __syncthreads();

    // ---- MLP per (kh, n); writes sM2u (overlays dead sDu) ----
    {
        int kh = tid >> 3, n = tid & 7;
        float xr[8], xi[8];
#pragma unroll
        for (int i = 0; i < 8; ++i) {
            float2 v = unpack2(sMu[kh * 66 + n * 8 + i]);
            xr[i] = v.x; xi[i] = v.y;
        }
        float o1r[8], o1i[8];
#pragma unroll
        for (int o = 0; o < 8; ++o) {
            float br = sb1[n * 8 + o], bi = sb1[64 + n * 8 + o];
            float sr = br - bi, si = br + bi;
#pragma unroll
            for (int i = 0; i < 8; ++i) {
                float wr = sW[0][(i * 8 + o) * 8 + n];
                float wi = sW[1][(i * 8 + o) * 8 + n];
                sr += xr[i] * wr - xi[i] * wi;
                si += xi[i] * wr + xr[i] * wi;
            }
            o1r[o] = gelu_exact(sr);
            o1i[o] = gelu_exact(si);
        }
#pragma unroll
        for (int o = 0; o < 8; ++o) {
            float br = sb2[n * 8 + o], bi = sb2[64 + n * 8 + o];
            float sr = br - bi, si = br + bi;
#pragma unroll
            for (int i = 0; i < 8; ++i) {
                float wr = sW[2][(i * 8 + o) * 8 + n];
                float wi = sW[3][(i * 8 + o) * 8 + n];
                sr += o1r[i] * wr - o1i[i] * wi;
                si += o1i[i] * wr + o1r[i] * wi;
            }
            sM2u[kh * 66 + n * 8 + o] = pack2(sr, si);
        }
    }
    __syncthreads();

    // ---- iDFT-H folded: out[h]=SE+SO, out[h+32]=SE-SO (2h x 4c tile) ----
    {
        int h0 = (tid >> 4) * 2;           // h0 in {0,2,...,30}
        int c0 = (tid & 15) * 4;           // complex col
        float SEr[2][4], SEi[2][4], SOr[2][4], SOi[2][4];
#pragma unroll
        for (int r = 0; r < 2; ++r)
#pragma unroll
            for (int j = 0; j < 4; ++j) {
                SEr[r][j] = 0.f; SEi[r][j] = 0.f;
                SOr[r][j] = 0.f; SOi[r][j] = 0.f;
            }
        for (int khp = 0; khp < 16; ++khp) {
#pragma unroll
            for (int par = 0; par < 2; ++par) {
                int kh = 2 * khp + par;
                float2 T0 = sT[h0 + 0][kh];
                float2 T1 = sT[h0 + 1][kh];
                const unsigned int* mp = sM2u + kh * 66 + c0;
                uint2 ua = *(const uint2*)(mp);
                uint2 ub = *(const uint2*)(mp + 2);
                float2 m0 = unpack2(ua.x), m1 = unpack2(ua.y);
                float2 m2 = unpack2(ub.x), m3 = unpack2(ub.y);
                float Mr[4] = {m0.x, m1.x, m2.x, m3.x};
                float Mi[4] = {m0.y, m1.y, m2.y, m3.y};
                float (*Sr)[4] = par ? SOr : SEr;
                float (*Si)[4] = par ? SOi : SEi;
                float Tr[2] = {T0.x, T1.x};
                float Ti[2] = {T0.y, T1.y};
#pragma unroll
                for (int r = 0; r < 2; ++r)
#pragma unroll
                    for (int j = 0; j < 4; ++j) {
                        // conj(T): stored (cos,-sin) -> multiply by (Tr, -Ti)
                        Sr[r][j] += Tr[r] * Mr[j] + Ti[r] * Mi[j];
                        Si[r][j] += Tr[r] * Mi[j] - Ti[r] * Mr[j];
                    }
            }
        }
        uint2* dst = (uint2*)z2f + (size_t)((b * 8 + kl) * 32 + kw) * 2048;
#pragma unroll
        for (int r = 0; r < 2; ++r) {
            int iA = (h0 + r) * 32 + (c0 >> 1);
            dst[iA]     = pack4(make_float4(SEr[r][0] + SOr[r][0], SEi[r][0] + SOi[r][0],
                                            SEr[r][1] + SOr[r][1], SEi[r][1] + SOi[r][1]));
            dst[iA + 1] = pack4(make_float4(SEr[r][2] + SOr[r][2], SEi[r][2] + SOi[r][2],
                                            SEr[r][3] + SOr[r][3], SEi[r][3] + SOi[r][3]));
            int iB = (h0 + 32 + r) * 32 + (c0 >> 1);
            dst[iB]     = pack4(make_float4(SEr[r][0] - SOr[r][0], SEi[r][0] - SOi[r][0],
                                            SEr[r][1] - SOr[r][1], SEi[r][1] - SOi[r][1]));
            dst[iB + 1] = pack4(make_float4(SEr[r][2] - SOr[r][2], SEi[r][2] - SOi[r][2],
                                            SEr[r][3] - SOr[r][3], SEi[r][3] - SOi[r][3]));
        }
    }
}

// ===========================================================================
// K3a: iDFT along W (32 modes -> 64), even/odd-kw fold. bf16 I/O.
// Block = (b, h, klq in [0,4)): 256 threads = 32 cp x 8 wq. Grid 1024.
// (unchanged, validated R11/R12)
__global__ void __launch_bounds__(256) k3a_idft_w(const unsigned int* __restrict__ z2f,
                                                  unsigned int* __restrict__ zwf) {
    __shared__ float4 sZ[2 * 32 * 32];   // 32 KB  [kli][kw][cp]
    __shared__ float2 twT[32][32];       // 8 KB   twT[w][kw] = e(+kw*w/64), w<32
    int tid = threadIdx.x;
#pragma unroll
    for (int e = 0; e < 4; ++e) {
        int idx = e * 256 + tid;         // 1024 entries
        int w = idx >> 5, kw = idx & 31;
        float s, c;
        sincosf(PI2_64 * (float)((w * kw) & 63), &s, &c);
        twT[w][kw] = make_float2(c, s);
    }
    int bid = blockIdx.x;                // (b*64+h)*4 + klq
    int klq = bid & 3, h = (bid >> 2) & 63, b = bid >> 8;
    const uint2* z2 = (const uint2*)z2f;
#pragma unroll
    for (int r = 0; r < 8; ++r) {
        int idx = r * 256 + tid;         // 0..2047 = (kli*32+kw)*32 + cp
        int row = idx >> 5, cp2 = idx & 31;
        int kli = row >> 5, kw = row & 31;
        sZ[idx] = unpack4(
            z2[((size_t)((b * 8 + klq * 2 + kli) * 32 + kw) * 64 + h) * 32 + cp2]);
    }
    __syncthreads();

    int cp = tid & 31, wq = tid >> 5;    // wq in [0,8)

    float4 E[2][4], O[2][4];
#pragma unroll
    for (int kli = 0; kli < 2; ++kli)
#pragma unroll
        for (int j = 0; j < 4; ++j) {
            E[kli][j] = make_float4(0.f, 0.f, 0.f, 0.f);
            O[kli][j] = make_float4(0.f, 0.f, 0.f, 0.f);
        }

    for (int kw = 0; kw < 32; kw += 2) {
#pragma unroll
        for (int kli = 0; kli < 2; ++kli) {
            float4 d = sZ[(kli * 32 + kw) * 32 + cp];
#pragma unroll
            for (int j = 0; j < 4; ++j) {
                float2 t = twT[wq * 4 + j][kw];
                E[kli][j].x += d.x * t.x - d.y * t.y;
                E[kli][j].y += d.y * t.x + d.x * t.y;
                E[kli][j].z += d.z * t.x - d.w * t.y;
                E[kli][j].w += d.w * t.x + d.z * t.y;
            }
        }
#pragma unroll
        for (int kli = 0; kli < 2; ++kli) {
            float4 d = sZ[(kli * 32 + kw + 1) * 32 + cp];
#pragma unroll
            for (int j = 0; j < 4; ++j) {
                float2 t = twT[wq * 4 + j][kw + 1];
                O[kli][j].x += d.x * t.x - d.y * t.y;
                O[kli][j].y += d.y * t.x + d.x * t.y;
                O[kli][j].z += d.z * t.x - d.w * t.y;
                O[kli][j].w += d.w * t.x + d.z * t.y;
            }
        }
    }
    uint2* zw = (uint2*)zwf;
    size_t slab = ((size_t)(b * 64 + h)) * 16384;   // 64w * 8kl * 32cp uint2
#pragma unroll
    for (int kli = 0; kli < 2; ++kli) {
        int kl = klq * 2 + kli;
#pragma unroll
        for (int j = 0; j < 4; ++j) {
            int w = wq * 4 + j;
            float4 e = E[kli][j], o = O[kli][j];
            zw[slab + ((size_t)w * 8 + kl) * 32 + cp] =
                pack4(make_float4(e.x + o.x, e.y + o.y, e.z + o.z, e.w + o.w));
            zw[slab + ((size_t)(w + 32) * 8 + kl) * 32 + cp] =
                pack4(make_float4(e.x - o.x, e.y - o.y, e.z - o.z, e.w - o.w));
        }
    }
}

// ===========================================================================
// K3b: iDFT along L (numpy irfft: Im(kl=0) dropped, modes 1..7 doubled),
// l/l+32 folded, + residual, 16 B/lane. (unchanged, validated R12)
__global__ void __launch_bounds__(256) k3b_idft_l(const float* __restrict__ x,
                                                  const unsigned int* __restrict__ zwf,
                                                  float* __restrict__ outp) {
    __shared__ float2 twA[8][32];        // 1 KB: twA[k][l] = e(+k*l/64), l<32
    int tid = threadIdx.x;
    if (tid < 256) {
        int k = tid >> 5, l = tid & 31;
        float s, c;
        sincosf(PI2_64 * (float)((k * l) & 63), &s, &c);
        twA[k][l] = make_float2(c, s);
    }
    __syncthreads();

    int bid = blockIdx.x;                // bh*4 + wg
    int wg = bid & 3, bh = bid >> 2;
    int cq = tid & 15, wl = tid >> 4;
    int w = wg * 16 + wl;

    const uint4* zw4 = (const uint4*)zwf;
    size_t zbase = ((size_t)(bh * 64 + w)) * 128 + cq;
    float4 z0[8], z1[8];                 // channels 4cq..4cq+1, 4cq+2..4cq+3
#pragma unroll
    for (int kl = 0; kl < 8; ++kl) {
        uint4 u = zw4[zbase + kl * 16];
        z0[kl] = unpack4(make_uint2(u.x, u.y));
        z1[kl] = unpack4(make_uint2(u.z, u.w));
    }

    float r00 = z0[0].x, r01 = z0[0].z;  // kl=0 real parts (Im dropped)
    float r10 = z1[0].x, r11 = z1[0].z;
#pragma unroll
    for (int kl = 1; kl < 8; ++kl) {     // pre-double modes 1..7
        z0[kl].x *= 2.f; z0[kl].y *= 2.f; z0[kl].z *= 2.f; z0[kl].w *= 2.f;
        z1[kl].x *= 2.f; z1[kl].y *= 2.f; z1[kl].z *= 2.f; z1[kl].w *= 2.f;
    }
    const size_t row = ((size_t)(bh * 64 + w)) * 4096;
    const float* xp = x + row + 4 * cq;
    float* op = outp + row + 4 * cq;
    const float sc = 1.0f / 512.0f;

    for (int l = 0; l < 32; ++l) {
        float4 a0 = *(const float4*)(xp + l * 64);
        float4 a1 = *(const float4*)(xp + (l + 32) * 64);
        float e00 = 0.f, e01 = 0.f, e10 = 0.f, e11 = 0.f;
        float o00 = 0.f, o01 = 0.f, o10 = 0.f, o11 = 0.f;
#pragma unroll
        for (int kl = 2; kl < 8; kl += 2) {
            float2 t = twA[kl][l];
            e00 += z0[kl].x * t.x - z0[kl].y * t.y;
            e01 += z0[kl].z * t.x - z0[kl].w * t.y;
            e10 += z1[kl].x * t.x - z1[kl].y * t.y;
            e11 += z1[kl].z * t.x - z1[kl].w * t.y;
        }
#pragma unroll
        for (int kl = 1; kl < 8; kl += 2) {
            float2 t = twA[kl][l];
            o00 += z0[kl].x * t.x - z0[kl].y * t.y;
            o01 += z0[kl].z * t.x - z0[kl].w * t.y;
            o10 += z1[kl].x * t.x - z1[kl].y * t.y;
            o11 += z1[kl].z * t.x - z1[kl].w * t.y;
        }
        float b00 = r00 + e00, b01 = r01 + e01;
        float b10 = r10 + e10, b11 = r11 + e11;
        *(float4*)(op + l * 64) = make_float4(
            (b00 + o00) * sc + a0.x, (b01 + o01) * sc + a0.y,
            (b10 + o10) * sc + a0.z, (b11 + o11) * sc + a0.w);
        *(float4*)(op + (l + 32) * 64) = make_float4(
            (b00 - o00) * sc + a1.x, (b01 - o01) * sc + a1.y,
            (b10 - o10) * sc + a1.z, (b11 - o11) * sc + a1.w);
    }
}

// ===========================================================================
extern "C" void kernel_launch(void* const* d_in, const int* in_sizes, int n_in,
                              void* d_out, int out_size, void* d_ws, size_t ws_size,
                              hipStream_t stream) {
    const float* x     = (const float*)d_in[0];
    const float* w1    = (const float*)d_in[1];
    const float* b1    = (const float*)d_in[2];
    const float* w2    = (const float*)d_in[3];
    const float* b2    = (const float*)d_in[4];
    const float* la1rA = (const float*)d_in[5];
    const float* la1rB = (const float*)d_in[6];
    const float* la1iA = (const float*)d_in[7];
    const float* la1iB = (const float*)d_in[8];
    const float* la2rA = (const float*)d_in[9];
    const float* la2rB = (const float*)d_in[10];
    const float* la2iA = (const float*)d_in[11];
    const float* la2iB = (const float*)d_in[12];
    float* out = (float*)d_out;

    unsigned int* ws = (unsigned int*)d_ws;
    unsigned int* y2 = ws;                 // 4194304 uint (16.8 MB)
    unsigned int* z2 = ws + 4194304;       // 4194304 uint (16.8 MB)
    unsigned int* zw = ws + 8388608;       // 8388608 uint (33.5 MB)

    hipLaunchKernelGGL(k1_fused,   dim3(512),  dim3(256), 0, stream, x, y2);
    hipLaunchKernelGGL(kc_h_mlp,   dim3(1024), dim3(256), 0, stream, y2, z2,
                       w1, b1, w2, b2, la1rA, la1rB, la1iA, la1iB,
                       la2rA, la2rB, la2iA, la2iB);
    hipLaunchKernelGGL(k3a_idft_w, dim3(1024), dim3(256), 0, stream, z2, zw);
    hipLaunchKernelGGL(k3b_idft_l, dim3(1024), dim3(256), 0, stream, x, zw, out);
}